// Round 1
// baseline (1365.113 us; speedup 1.0000x reference)
//
#include <hip/hip_runtime.h>
#include <hip/hip_bf16.h>
#include <hip/hip_fp16.h>

#define SEQ 8192
#define DM  1024   // d_in == d_out == 1024

typedef __attribute__((ext_vector_type(8))) short   bf16x8;
typedef __attribute__((ext_vector_type(8))) _Float16 f16x8;
typedef __attribute__((ext_vector_type(4))) float    f32x4;

union H8 { _Float16 h[8]; int4 v; };

__device__ __forceinline__ unsigned short f2bf(float f) {
    union { float f; unsigned u; } x; x.f = f;
    unsigned r = x.u + 0x7fffu + ((x.u >> 16) & 1u);
    return (unsigned short)(r >> 16);
}
__device__ __forceinline__ float bf2f(unsigned short h) {
    union { unsigned u; float f; } x; x.u = ((unsigned)h) << 16;
    return x.f;
}

// ---------------- K1a: split x (fp32 -> bf16 hi/lo), elementwise ----------------
__global__ __launch_bounds__(256) void split_x_kernel(const float* __restrict__ x,
    unsigned short* __restrict__ xhi, unsigned short* __restrict__ xlo, int n)
{
    int base = (blockIdx.x * 256 + threadIdx.x) * 4;
    if (base >= n) return;
    float4 v = *(const float4*)(x + base);
    float f[4] = {v.x, v.y, v.z, v.w};
    unsigned short h[4], l[4];
#pragma unroll
    for (int j = 0; j < 4; j++) { h[j] = f2bf(f[j]); l[j] = f2bf(f[j] - bf2f(h[j])); }
    ushort4 hv = {h[0], h[1], h[2], h[3]};
    ushort4 lv = {l[0], l[1], l[2], l[3]};
    *(ushort4*)(xhi + base) = hv;
    *(ushort4*)(xlo + base) = lv;
}

// ------------- K1b: transpose + split W [1024k x 1024n] -> Wt hi/lo [n][k] -------------
__global__ __launch_bounds__(256) void wsplit_t_kernel(const float* __restrict__ W,
    unsigned short* __restrict__ Wthi, unsigned short* __restrict__ Wtlo)
{
    __shared__ float tile[64][65];
    int bn = blockIdx.x * 64;   // cols of W (output rows of Wt)
    int bk = blockIdx.y * 64;   // rows of W
    int t = threadIdx.x;
#pragma unroll
    for (int p = 0; p < 4; p++) {
        int r = p * 16 + (t >> 4);
        int c = (t & 15) * 4;
        float4 v = *(const float4*)(W + (size_t)(bk + r) * DM + bn + c);
        tile[r][c] = v.x; tile[r][c+1] = v.y; tile[r][c+2] = v.z; tile[r][c+3] = v.w;
    }
    __syncthreads();
#pragma unroll
    for (int p = 0; p < 2; p++) {
        int task = p * 256 + t;
        int rn = task >> 3;          // 0..63 : Wt row within tile (n)
        int kc = (task & 7) * 8;     // 0..56 : Wt col chunk (k)
        union { unsigned short u[8]; int4 v; } hh, ll;
#pragma unroll
        for (int j = 0; j < 8; j++) {
            float f = tile[kc + j][rn];
            hh.u[j] = f2bf(f);
            ll.u[j] = f2bf(f - bf2f(hh.u[j]));
        }
        size_t o = (size_t)(bn + rn) * DM + bk + kc;
        *(int4*)(Wthi + o) = hh.v;
        *(int4*)(Wtlo + o) = ll.v;
    }
}

// ---------------- generic 64x64-tile GEMM over contraction K=1024 ----------------
// A:[M x 1024] row-major bf16 (hi/lo). B:[N x 1024] row-major bf16 ("B^T" layout, hi/lo).
// MODE 0: split compute, split bf16 output (Q/K projection)
// MODE 1: plain compute, f16 output (V projection)
// MODE 2: split compute, scores epilogue: scale, tile rowmax -> T, fp16(S - max) -> S16
template<int MODE>
__global__ __launch_bounds__(256) void gemm1024(
    const unsigned short* __restrict__ Ahi, const unsigned short* __restrict__ Alo,
    const unsigned short* __restrict__ Bhi, const unsigned short* __restrict__ Blo,
    unsigned short* __restrict__ Chi, unsigned short* __restrict__ Clo,
    _Float16* __restrict__ Cf16,
    _Float16* __restrict__ S16o, float* __restrict__ T)
{
    constexpr bool SPLIT = (MODE != 1);
    __shared__ unsigned short sAhi[64 * 32], sAlo[64 * 32];
    __shared__ unsigned short sBhi[64 * 32], sBlo[64 * 32];

    const int m0 = blockIdx.y * 64, n0 = blockIdx.x * 64;
    const int t = threadIdx.x;
    const int wave = t >> 6, lane = t & 63;
    const int i16 = lane & 15, quad = lane >> 4;

    const int srow = t >> 2, scol = (t & 3) * 8;
    const int soff = srow * 32 + scol;
    const unsigned short* pAhi = Ahi + (size_t)(m0 + srow) * DM + scol;
    const unsigned short* pAlo = SPLIT ? (Alo + (size_t)(m0 + srow) * DM + scol) : pAhi;
    const unsigned short* pBhi = Bhi + (size_t)(n0 + srow) * DM + scol;
    const unsigned short* pBlo = SPLIT ? (Blo + (size_t)(n0 + srow) * DM + scol) : pBhi;

    f32x4 acc[4] = {};

    for (int k = 0; k < 1024; k += 32) {
        __syncthreads();
        *(int4*)(sAhi + soff) = *(const int4*)(pAhi + k);
        *(int4*)(sBhi + soff) = *(const int4*)(pBhi + k);
        if constexpr (SPLIT) {
            *(int4*)(sAlo + soff) = *(const int4*)(pAlo + k);
            *(int4*)(sBlo + soff) = *(const int4*)(pBlo + k);
        }
        __syncthreads();
        bf16x8 ahi = *(bf16x8*)(sAhi + (wave * 16 + i16) * 32 + quad * 8);
        bf16x8 alo;
        if constexpr (SPLIT) alo = *(bf16x8*)(sAlo + (wave * 16 + i16) * 32 + quad * 8);
#pragma unroll
        for (int nt = 0; nt < 4; nt++) {
            bf16x8 bhi = *(bf16x8*)(sBhi + (nt * 16 + i16) * 32 + quad * 8);
            acc[nt] = __builtin_amdgcn_mfma_f32_16x16x32_bf16(ahi, bhi, acc[nt], 0, 0, 0);
            if constexpr (SPLIT) {
                bf16x8 blo = *(bf16x8*)(sBlo + (nt * 16 + i16) * 32 + quad * 8);
                acc[nt] = __builtin_amdgcn_mfma_f32_16x16x32_bf16(ahi, blo, acc[nt], 0, 0, 0);
                acc[nt] = __builtin_amdgcn_mfma_f32_16x16x32_bf16(alo, bhi, acc[nt], 0, 0, 0);
            }
        }
    }

    if constexpr (MODE == 0) {
#pragma unroll
        for (int nt = 0; nt < 4; nt++)
#pragma unroll
            for (int r = 0; r < 4; r++) {
                int row = m0 + wave * 16 + quad * 4 + r;
                int col = n0 + nt * 16 + i16;
                float v = acc[nt][r];
                unsigned short h = f2bf(v);
                Chi[(size_t)row * DM + col] = h;
                Clo[(size_t)row * DM + col] = f2bf(v - bf2f(h));
            }
    } else if constexpr (MODE == 1) {
#pragma unroll
        for (int nt = 0; nt < 4; nt++)
#pragma unroll
            for (int r = 0; r < 4; r++) {
                int row = m0 + wave * 16 + quad * 4 + r;
                int col = n0 + nt * 16 + i16;
                Cf16[(size_t)row * DM + col] = (_Float16)acc[nt][r];
            }
    } else {
        const float scale = 0.03125f;  // 1/sqrt(1024)
        float sv[4][4];
#pragma unroll
        for (int nt = 0; nt < 4; nt++)
#pragma unroll
            for (int r = 0; r < 4; r++) sv[nt][r] = acc[nt][r] * scale;
#pragma unroll
        for (int r = 0; r < 4; r++) {
            float mx = fmaxf(fmaxf(sv[0][r], sv[1][r]), fmaxf(sv[2][r], sv[3][r]));
            mx = fmaxf(mx, __shfl_xor(mx, 1));
            mx = fmaxf(mx, __shfl_xor(mx, 2));
            mx = fmaxf(mx, __shfl_xor(mx, 4));
            mx = fmaxf(mx, __shfl_xor(mx, 8));
            int row = m0 + wave * 16 + quad * 4 + r;
            if (i16 == 0) T[row * 128 + (n0 >> 6)] = mx;
#pragma unroll
            for (int nt = 0; nt < 4; nt++)
                S16o[(size_t)row * SEQ + n0 + nt * 16 + i16] = (_Float16)(sv[nt][r] - mx);
        }
    }
}

// ---------------- K3: transpose V [8192 x 1024] f16 -> Vt [1024 x 8192] ----------------
__global__ __launch_bounds__(256) void transpose_f16(const _Float16* __restrict__ in,
                                                     _Float16* __restrict__ out)
{
    __shared__ _Float16 tile[64][72];
    int bn = blockIdx.x * 64;   // cols of in (d_out)
    int bm = blockIdx.y * 64;   // rows of in (seq)
    int t = threadIdx.x;
    int r = t >> 3, c = (t & 7) * 8;
#pragma unroll
    for (int p = 0; p < 2; p++) {
        int rr = p * 32 + r;
        H8 v; v.v = *(const int4*)(in + (size_t)(bm + rr) * DM + bn + c);
#pragma unroll
        for (int j = 0; j < 8; j++) tile[rr][c + j] = v.h[j];
    }
    __syncthreads();
#pragma unroll
    for (int p = 0; p < 2; p++) {
        int rr = p * 32 + r;
        H8 v;
#pragma unroll
        for (int j = 0; j < 8; j++) v.h[j] = tile[c + j][rr];
        *(int4*)(out + (size_t)(bn + rr) * SEQ + bm + c) = v.v;
    }
}

// ---------------- K5: per-row softmax stats m, l from S16 + T ----------------
__global__ __launch_bounds__(256) void row_stats(const _Float16* __restrict__ S16,
    const float* __restrict__ T, float* __restrict__ Mr, float* __restrict__ Lr)
{
    int row = blockIdx.x;
    int t = threadIdx.x;
    int wave = t >> 6, lane = t & 63;
    const _Float16* pr = S16 + (size_t)row * SEQ;
    const float* pt = T + row * 128;
    __shared__ float red[4];
    __shared__ float mfin;

    float mx = -3.0e38f;
    for (int c = t * 8; c < SEQ; c += 2048) {
        H8 v; v.v = *(const int4*)(pr + c);
        float tb = pt[c >> 6];
#pragma unroll
        for (int j = 0; j < 8; j++) mx = fmaxf(mx, (float)v.h[j] + tb);
    }
    for (int sh = 1; sh < 64; sh <<= 1) mx = fmaxf(mx, __shfl_xor(mx, sh));
    if (lane == 0) red[wave] = mx;
    __syncthreads();
    if (t == 0) mfin = fmaxf(fmaxf(red[0], red[1]), fmaxf(red[2], red[3]));
    __syncthreads();
    float m = mfin;

    float s = 0.f;
    for (int c = t * 8; c < SEQ; c += 2048) {
        H8 v; v.v = *(const int4*)(pr + c);
        float tb = pt[c >> 6] - m;
#pragma unroll
        for (int j = 0; j < 8; j++) s += __expf((float)v.h[j] + tb);
    }
    for (int sh = 1; sh < 64; sh <<= 1) s += __shfl_xor(s, sh);
    __syncthreads();
    if (lane == 0) red[wave] = s;
    __syncthreads();
    if (t == 0) { Mr[row] = m; Lr[row] = red[0] + red[1] + red[2] + red[3]; }
}

// ---------------- K6: O = softmax(S) @ V, fused P-dequant GEMM, K-dim = 8192 ----------------
__global__ __launch_bounds__(256) void gemm_pv(const _Float16* __restrict__ S16,
    const float* __restrict__ T, const float* __restrict__ Mr, const float* __restrict__ Lr,
    const _Float16* __restrict__ Vt, float* __restrict__ O)
{
    __shared__ _Float16 sP[64 * 32], sV[64 * 32];
    __shared__ float sm[64], sli[64];

    const int m0 = blockIdx.y * 64, n0 = blockIdx.x * 64;
    const int t = threadIdx.x;
    const int wave = t >> 6, lane = t & 63;
    const int i16 = lane & 15, quad = lane >> 4;
    const int srow = t >> 2, scol = (t & 3) * 8;
    const int soff = srow * 32 + scol;

    if (t < 64) { sm[t] = Mr[m0 + t]; sli[t] = 1.0f / Lr[m0 + t]; }

    f32x4 acc[4] = {};
    const _Float16* pS = S16 + (size_t)(m0 + srow) * SEQ + scol;
    const _Float16* pV = Vt + (size_t)(n0 + srow) * SEQ + scol;
    const float* pT = T + (m0 + srow) * 128;

    for (int k = 0; k < SEQ; k += 32) {
        __syncthreads();
        {
            H8 in; in.v = *(const int4*)(pS + k);
            float tb = pT[k >> 6] - sm[srow];
            float li = sli[srow];
            H8 pp;
#pragma unroll
            for (int j = 0; j < 8; j++)
                pp.h[j] = (_Float16)(__expf((float)in.h[j] + tb) * li);
            *(int4*)(sP + soff) = pp.v;
        }
        *(int4*)(sV + soff) = *(const int4*)(pV + k);
        __syncthreads();
        f16x8 a = *(f16x8*)(sP + (wave * 16 + i16) * 32 + quad * 8);
#pragma unroll
        for (int nt = 0; nt < 4; nt++) {
            f16x8 b = *(f16x8*)(sV + (nt * 16 + i16) * 32 + quad * 8);
            acc[nt] = __builtin_amdgcn_mfma_f32_16x16x32_f16(a, b, acc[nt], 0, 0, 0);
        }
    }
#pragma unroll
    for (int nt = 0; nt < 4; nt++)
#pragma unroll
        for (int r = 0; r < 4; r++) {
            int row = m0 + wave * 16 + quad * 4 + r;
            int col = n0 + nt * 16 + i16;
            O[(size_t)row * DM + col] = acc[nt][r];
        }
}

extern "C" void kernel_launch(void* const* d_in, const int* in_sizes, int n_in,
                              void* d_out, int out_size, void* d_ws, size_t ws_size,
                              hipStream_t stream)
{
    const float* x  = (const float*)d_in[0];
    const float* Wq = (const float*)d_in[1];
    const float* Wk = (const float*)d_in[2];
    const float* Wv = (const float*)d_in[3];
    float* Out = (float*)d_out;
    char* ws = (char*)d_ws;

    const size_t MB = 1024 * 1024;
    // Region [0, 128MB): first holds x-splits / W-splits / Vtmp, later S16 (after they are dead)
    unsigned short* xhi   = (unsigned short*)(ws + 0 * MB);
    unsigned short* xlo   = (unsigned short*)(ws + 16 * MB);
    unsigned short* Wqthi = (unsigned short*)(ws + 32 * MB);
    unsigned short* Wqtlo = (unsigned short*)(ws + 34 * MB);
    unsigned short* Wkthi = (unsigned short*)(ws + 36 * MB);
    unsigned short* Wktlo = (unsigned short*)(ws + 38 * MB);
    unsigned short* Wvthi = (unsigned short*)(ws + 40 * MB);
    unsigned short* Wvtlo = (unsigned short*)(ws + 42 * MB);
    _Float16*       Vtmp  = (_Float16*)     (ws + 44 * MB);   // 16 MB, dead after transpose
    _Float16*       S16   = (_Float16*)     (ws + 0 * MB);    // 128 MB, written after Vtmp dead

    size_t off = 128 * MB;
    unsigned short* Qhi = (unsigned short*)(ws + off); off += 16 * MB;
    unsigned short* Qlo = (unsigned short*)(ws + off); off += 16 * MB;
    unsigned short* Khi = (unsigned short*)(ws + off); off += 16 * MB;
    unsigned short* Klo = (unsigned short*)(ws + off); off += 16 * MB;
    _Float16*       Vt  = (_Float16*)      (ws + off); off += 16 * MB;
    float*          T   = (float*)         (ws + off); off += (size_t)SEQ * 128 * 4;
    float*          Mr  = (float*)         (ws + off); off += SEQ * 4;
    float*          Lr  = (float*)         (ws + off); off += SEQ * 4;

    // 1. split x
    split_x_kernel<<<(SEQ * DM) / (256 * 4), 256, 0, stream>>>(x, xhi, xlo, SEQ * DM);
    // 2. transpose+split weights
    dim3 wgrid(16, 16);
    wsplit_t_kernel<<<wgrid, 256, 0, stream>>>(Wq, Wqthi, Wqtlo);
    wsplit_t_kernel<<<wgrid, 256, 0, stream>>>(Wk, Wkthi, Wktlo);
    wsplit_t_kernel<<<wgrid, 256, 0, stream>>>(Wv, Wvthi, Wvtlo);
    // 3. projections
    dim3 pgrid(DM / 64, SEQ / 64);
    gemm1024<0><<<pgrid, 256, 0, stream>>>(xhi, xlo, Wqthi, Wqtlo, Qhi, Qlo, nullptr, nullptr, nullptr);
    gemm1024<0><<<pgrid, 256, 0, stream>>>(xhi, xlo, Wkthi, Wktlo, Khi, Klo, nullptr, nullptr, nullptr);
    gemm1024<1><<<pgrid, 256, 0, stream>>>(xhi, nullptr, Wvthi, nullptr, nullptr, nullptr, Vtmp, nullptr, nullptr);
    // 4. transpose V
    transpose_f16<<<dim3(DM / 64, SEQ / 64), 256, 0, stream>>>(Vtmp, Vt);
    // 5. scores -> S16 (fp16 rel tile-max) + T
    dim3 sgrid(SEQ / 64, SEQ / 64);
    gemm1024<2><<<sgrid, 256, 0, stream>>>(Qhi, Qlo, Khi, Klo, nullptr, nullptr, nullptr, S16, T);
    // 6. row stats
    row_stats<<<SEQ, 256, 0, stream>>>(S16, T, Mr, Lr);
    // 7. O = P @ V
    gemm_pv<<<dim3(DM / 64, SEQ / 64), 256, 0, stream>>>(S16, T, Mr, Lr, Vt, Out);
}

// Round 2
// 932.937 us; speedup vs baseline: 1.4632x; 1.4632x over previous
//
#include <hip/hip_runtime.h>
#include <hip/hip_bf16.h>
#include <hip/hip_fp16.h>

#define SEQ 8192
#define DM  1024   // d_in == d_out == 1024

typedef __attribute__((ext_vector_type(8))) short   bf16x8;
typedef __attribute__((ext_vector_type(8))) _Float16 f16x8;
typedef __attribute__((ext_vector_type(4))) float    f32x4;

union H8 { _Float16 h[8]; int4 v; };

__device__ __forceinline__ unsigned short f2bf(float f) {
    union { float f; unsigned u; } x; x.f = f;
    unsigned r = x.u + 0x7fffu + ((x.u >> 16) & 1u);
    return (unsigned short)(r >> 16);
}
__device__ __forceinline__ float bf2f(unsigned short h) {
    union { unsigned u; float f; } x; x.u = ((unsigned)h) << 16;
    return x.f;
}

// async global->LDS, 16B per lane; lds dest must be wave-uniform (HW adds lane*16)
__device__ __forceinline__ void gld16(const unsigned short* g, unsigned short* l) {
    __builtin_amdgcn_global_load_lds(
        (const __attribute__((address_space(1))) void*)g,
        (__attribute__((address_space(3))) void*)l, 16, 0, 0);
}

// ---------------- K1a: split x (fp32 -> bf16 hi/lo), elementwise ----------------
__global__ __launch_bounds__(256) void split_x_kernel(const float* __restrict__ x,
    unsigned short* __restrict__ xhi, unsigned short* __restrict__ xlo, int n)
{
    int base = (blockIdx.x * 256 + threadIdx.x) * 4;
    if (base >= n) return;
    float4 v = *(const float4*)(x + base);
    float f[4] = {v.x, v.y, v.z, v.w};
    unsigned short h[4], l[4];
#pragma unroll
    for (int j = 0; j < 4; j++) { h[j] = f2bf(f[j]); l[j] = f2bf(f[j] - bf2f(h[j])); }
    ushort4 hv = {h[0], h[1], h[2], h[3]};
    ushort4 lv = {l[0], l[1], l[2], l[3]};
    *(ushort4*)(xhi + base) = hv;
    *(ushort4*)(xlo + base) = lv;
}

// ------------- K1b: transpose + split W [1024k x 1024n] -> Wt hi/lo [n][k] -------------
__global__ __launch_bounds__(256) void wsplit_t_kernel(const float* __restrict__ W,
    unsigned short* __restrict__ Wthi, unsigned short* __restrict__ Wtlo)
{
    __shared__ float tile[64][65];
    int bn = blockIdx.x * 64;
    int bk = blockIdx.y * 64;
    int t = threadIdx.x;
#pragma unroll
    for (int p = 0; p < 4; p++) {
        int r = p * 16 + (t >> 4);
        int c = (t & 15) * 4;
        float4 v = *(const float4*)(W + (size_t)(bk + r) * DM + bn + c);
        tile[r][c] = v.x; tile[r][c+1] = v.y; tile[r][c+2] = v.z; tile[r][c+3] = v.w;
    }
    __syncthreads();
#pragma unroll
    for (int p = 0; p < 2; p++) {
        int task = p * 256 + t;
        int rn = task >> 3;
        int kc = (task & 7) * 8;
        union { unsigned short u[8]; int4 v; } hh, ll;
#pragma unroll
        for (int j = 0; j < 8; j++) {
            float f = tile[kc + j][rn];
            hh.u[j] = f2bf(f);
            ll.u[j] = f2bf(f - bf2f(hh.u[j]));
        }
        size_t o = (size_t)(bn + rn) * DM + bk + kc;
        *(int4*)(Wthi + o) = hh.v;
        *(int4*)(Wtlo + o) = ll.v;
    }
}

// ============ unified 128x128-tile GEMM, global_load_lds staging, BK=32 ============
// A:[M x KD], B:[N x KD] row-major (contraction contiguous), ushort elements.
// MODE 0: split bf16 compute -> split bf16 out (Q/K projection), KD=1024
// MODE 1: plain bf16 compute -> f16 out (V projection), KD=1024
// MODE 2: split bf16 compute -> scores epilogue (scale, 64-col tile rowmax T, f16 S-max), KD=1024
// MODE 3: plain f16 compute -> f32 out (PV), KD=8192
template<int MODE, int KD>
__global__ __launch_bounds__(256) void gemm128(
    const unsigned short* __restrict__ A,  const unsigned short* __restrict__ Alo,
    const unsigned short* __restrict__ B,  const unsigned short* __restrict__ Blo,
    unsigned short* __restrict__ Chi, unsigned short* __restrict__ Clo,
    _Float16* __restrict__ Cf16, float* __restrict__ Cf32,
    _Float16* __restrict__ S16o, float* __restrict__ T)
{
    constexpr bool SPLIT = (MODE == 0 || MODE == 2);
    __shared__ alignas(16) unsigned short sAhi[128 * 32];
    __shared__ alignas(16) unsigned short sBhi[128 * 32];
    __shared__ alignas(16) unsigned short sAlo[SPLIT ? 128 * 32 : 16];
    __shared__ alignas(16) unsigned short sBlo[SPLIT ? 128 * 32 : 16];

    const int m0 = blockIdx.y * 128, n0 = blockIdx.x * 128;
    const int t = threadIdx.x;
    const int wave = t >> 6, lane = t & 63;
    const int wr = wave >> 1, wc = wave & 1;    // wave quadrant (64x64)
    const int i16 = lane & 15, quad = lane >> 4;

    // staging slot: lane covers row rs (i=0) / rs+16 (i=1), cols cs..cs+7
    const int rs = wave * 32 + (lane >> 2);
    const int cs = (lane & 3) * 8;
    const size_t aoff = (size_t)(m0 + rs) * KD + cs;
    const size_t boff = (size_t)(n0 + rs) * KD + cs;
    const int ldsb = wave * 1024;   // element offset of this wave's staging region

    f32x4 acc[4][4] = {};

    for (int k = 0; k < KD; k += 32) {
        __syncthreads();
        gld16(A + aoff + k,            sAhi + ldsb);
        gld16(A + aoff + 16 * KD + k,  sAhi + ldsb + 512);
        gld16(B + boff + k,            sBhi + ldsb);
        gld16(B + boff + 16 * KD + k,  sBhi + ldsb + 512);
        if constexpr (SPLIT) {
            gld16(Alo + aoff + k,           sAlo + ldsb);
            gld16(Alo + aoff + 16 * KD + k, sAlo + ldsb + 512);
            gld16(Blo + boff + k,           sBlo + ldsb);
            gld16(Blo + boff + 16 * KD + k, sBlo + ldsb + 512);
        }
        __syncthreads();

        bf16x8 ahi[4], alo[4];
#pragma unroll
        for (int mt = 0; mt < 4; mt++) {
            int r = wr * 64 + mt * 16 + i16;
            ahi[mt] = *(const bf16x8*)(sAhi + r * 32 + quad * 8);
            if constexpr (SPLIT) alo[mt] = *(const bf16x8*)(sAlo + r * 32 + quad * 8);
        }
#pragma unroll
        for (int nt = 0; nt < 4; nt++) {
            int r = wc * 64 + nt * 16 + i16;
            bf16x8 bhi = *(const bf16x8*)(sBhi + r * 32 + quad * 8);
            bf16x8 blo;
            if constexpr (SPLIT) blo = *(const bf16x8*)(sBlo + r * 32 + quad * 8);
#pragma unroll
            for (int mt = 0; mt < 4; mt++) {
                if constexpr (MODE == 3) {
                    acc[mt][nt] = __builtin_amdgcn_mfma_f32_16x16x32_f16(
                        __builtin_bit_cast(f16x8, ahi[mt]), __builtin_bit_cast(f16x8, bhi),
                        acc[mt][nt], 0, 0, 0);
                } else {
                    acc[mt][nt] = __builtin_amdgcn_mfma_f32_16x16x32_bf16(ahi[mt], bhi, acc[mt][nt], 0, 0, 0);
                    if constexpr (SPLIT) {
                        acc[mt][nt] = __builtin_amdgcn_mfma_f32_16x16x32_bf16(ahi[mt], blo, acc[mt][nt], 0, 0, 0);
                        acc[mt][nt] = __builtin_amdgcn_mfma_f32_16x16x32_bf16(alo[mt], bhi, acc[mt][nt], 0, 0, 0);
                    }
                }
            }
        }
    }

    // ---------------- epilogues ----------------
    if constexpr (MODE == 0) {
#pragma unroll
        for (int mt = 0; mt < 4; mt++)
#pragma unroll
            for (int nt = 0; nt < 4; nt++)
#pragma unroll
                for (int r = 0; r < 4; r++) {
                    int row = m0 + wr * 64 + mt * 16 + quad * 4 + r;
                    int col = n0 + wc * 64 + nt * 16 + i16;
                    float v = acc[mt][nt][r];
                    unsigned short h = f2bf(v);
                    Chi[(size_t)row * DM + col] = h;
                    Clo[(size_t)row * DM + col] = f2bf(v - bf2f(h));
                }
    } else if constexpr (MODE == 1) {
#pragma unroll
        for (int mt = 0; mt < 4; mt++)
#pragma unroll
            for (int nt = 0; nt < 4; nt++)
#pragma unroll
                for (int r = 0; r < 4; r++) {
                    int row = m0 + wr * 64 + mt * 16 + quad * 4 + r;
                    int col = n0 + wc * 64 + nt * 16 + i16;
                    Cf16[(size_t)row * DM + col] = (_Float16)acc[mt][nt][r];
                }
    } else if constexpr (MODE == 3) {
#pragma unroll
        for (int mt = 0; mt < 4; mt++)
#pragma unroll
            for (int nt = 0; nt < 4; nt++)
#pragma unroll
                for (int r = 0; r < 4; r++) {
                    int row = m0 + wr * 64 + mt * 16 + quad * 4 + r;
                    int col = n0 + wc * 64 + nt * 16 + i16;
                    Cf32[(size_t)row * DM + col] = acc[mt][nt][r];
                }
    } else {  // MODE 2: scores
        const float scale = 0.03125f;  // 1/sqrt(1024)
#pragma unroll
        for (int mt = 0; mt < 4; mt++)
#pragma unroll
            for (int r = 0; r < 4; r++) {
                float s0 = acc[mt][0][r] * scale, s1 = acc[mt][1][r] * scale;
                float s2 = acc[mt][2][r] * scale, s3 = acc[mt][3][r] * scale;
                float mx = fmaxf(fmaxf(s0, s1), fmaxf(s2, s3));
                mx = fmaxf(mx, __shfl_xor(mx, 1));
                mx = fmaxf(mx, __shfl_xor(mx, 2));
                mx = fmaxf(mx, __shfl_xor(mx, 4));
                mx = fmaxf(mx, __shfl_xor(mx, 8));
                int row = m0 + wr * 64 + mt * 16 + quad * 4 + r;
                if (i16 == 0) T[row * 128 + ((n0 + wc * 64) >> 6)] = mx;
                S16o[(size_t)row * SEQ + n0 + wc * 64 +  0 + i16] = (_Float16)(s0 - mx);
                S16o[(size_t)row * SEQ + n0 + wc * 64 + 16 + i16] = (_Float16)(s1 - mx);
                S16o[(size_t)row * SEQ + n0 + wc * 64 + 32 + i16] = (_Float16)(s2 - mx);
                S16o[(size_t)row * SEQ + n0 + wc * 64 + 48 + i16] = (_Float16)(s3 - mx);
            }
    }
}

// ---------------- K3: transpose V [8192 x 1024] f16 -> Vt [1024 x 8192] ----------------
__global__ __launch_bounds__(256) void transpose_f16(const _Float16* __restrict__ in,
                                                     _Float16* __restrict__ out)
{
    __shared__ _Float16 tile[64][72];
    int bn = blockIdx.x * 64;
    int bm = blockIdx.y * 64;
    int t = threadIdx.x;
    int r = t >> 3, c = (t & 7) * 8;
#pragma unroll
    for (int p = 0; p < 2; p++) {
        int rr = p * 32 + r;
        H8 v; v.v = *(const int4*)(in + (size_t)(bm + rr) * DM + bn + c);
#pragma unroll
        for (int j = 0; j < 8; j++) tile[rr][c + j] = v.h[j];
    }
    __syncthreads();
#pragma unroll
    for (int p = 0; p < 2; p++) {
        int rr = p * 32 + r;
        H8 v;
#pragma unroll
        for (int j = 0; j < 8; j++) v.h[j] = tile[c + j][rr];
        *(int4*)(out + (size_t)(bn + rr) * SEQ + bm + c) = v.v;
    }
}

// ---------------- K5: per-row softmax stats m, l from S16 + T ----------------
__global__ __launch_bounds__(256) void row_stats(const _Float16* __restrict__ S16,
    const float* __restrict__ T, float* __restrict__ Mr, float* __restrict__ Lr)
{
    int row = blockIdx.x;
    int t = threadIdx.x;
    int wave = t >> 6, lane = t & 63;
    const _Float16* pr = S16 + (size_t)row * SEQ;
    const float* pt = T + row * 128;
    __shared__ float red[4];
    __shared__ float mfin;

    float mx = -3.0e38f;
    for (int c = t * 8; c < SEQ; c += 2048) {
        H8 v; v.v = *(const int4*)(pr + c);
        float tb = pt[c >> 6];
#pragma unroll
        for (int j = 0; j < 8; j++) mx = fmaxf(mx, (float)v.h[j] + tb);
    }
    for (int sh = 1; sh < 64; sh <<= 1) mx = fmaxf(mx, __shfl_xor(mx, sh));
    if (lane == 0) red[wave] = mx;
    __syncthreads();
    if (t == 0) mfin = fmaxf(fmaxf(red[0], red[1]), fmaxf(red[2], red[3]));
    __syncthreads();
    float m = mfin;

    float s = 0.f;
    for (int c = t * 8; c < SEQ; c += 2048) {
        H8 v; v.v = *(const int4*)(pr + c);
        float tb = pt[c >> 6] - m;
#pragma unroll
        for (int j = 0; j < 8; j++) s += __expf((float)v.h[j] + tb);
    }
    for (int sh = 1; sh < 64; sh <<= 1) s += __shfl_xor(s, sh);
    __syncthreads();
    if (lane == 0) red[wave] = s;
    __syncthreads();
    if (t == 0) { Mr[row] = m; Lr[row] = red[0] + red[1] + red[2] + red[3]; }
}

// ---------------- K5b: in-place S16 -> P16 = exp(s + T - m - ln(l)) ----------------
__global__ __launch_bounds__(256) void p_pass(_Float16* __restrict__ S16,
    const float* __restrict__ T, const float* __restrict__ Mr, const float* __restrict__ Lr)
{
    int row = blockIdx.x;
    float m = Mr[row], lnl = __logf(Lr[row]);
    const float* pt = T + row * 128;
    _Float16* pr = S16 + (size_t)row * SEQ;
    for (int c = threadIdx.x * 8; c < SEQ; c += 2048) {
        H8 v; v.v = *(const int4*)(pr + c);
        float C = pt[c >> 6] - m - lnl;
        H8 o;
#pragma unroll
        for (int j = 0; j < 8; j++) o.h[j] = (_Float16)__expf((float)v.h[j] + C);
        *(int4*)(pr + c) = o.v;
    }
}

extern "C" void kernel_launch(void* const* d_in, const int* in_sizes, int n_in,
                              void* d_out, int out_size, void* d_ws, size_t ws_size,
                              hipStream_t stream)
{
    const float* x  = (const float*)d_in[0];
    const float* Wq = (const float*)d_in[1];
    const float* Wk = (const float*)d_in[2];
    const float* Wv = (const float*)d_in[3];
    float* Out = (float*)d_out;
    char* ws = (char*)d_ws;

    const size_t MB = 1024 * 1024;
    // Region [0, 128MB): first holds x-splits / W-splits / Vtmp, later S16 (after they are dead)
    unsigned short* xhi   = (unsigned short*)(ws + 0 * MB);
    unsigned short* xlo   = (unsigned short*)(ws + 16 * MB);
    unsigned short* Wqthi = (unsigned short*)(ws + 32 * MB);
    unsigned short* Wqtlo = (unsigned short*)(ws + 34 * MB);
    unsigned short* Wkthi = (unsigned short*)(ws + 36 * MB);
    unsigned short* Wktlo = (unsigned short*)(ws + 38 * MB);
    unsigned short* Wvthi = (unsigned short*)(ws + 40 * MB);
    unsigned short* Wvtlo = (unsigned short*)(ws + 42 * MB);
    _Float16*       Vtmp  = (_Float16*)     (ws + 44 * MB);   // dead after transpose
    _Float16*       S16   = (_Float16*)     (ws + 0 * MB);    // 128 MB, written after Vtmp dead

    size_t off = 128 * MB;
    unsigned short* Qhi = (unsigned short*)(ws + off); off += 16 * MB;
    unsigned short* Qlo = (unsigned short*)(ws + off); off += 16 * MB;
    unsigned short* Khi = (unsigned short*)(ws + off); off += 16 * MB;
    unsigned short* Klo = (unsigned short*)(ws + off); off += 16 * MB;
    _Float16*       Vt  = (_Float16*)      (ws + off); off += 16 * MB;
    float*          T   = (float*)         (ws + off); off += (size_t)SEQ * 128 * 4;
    float*          Mr  = (float*)         (ws + off); off += SEQ * 4;
    float*          Lr  = (float*)         (ws + off); off += SEQ * 4;

    // 1. split x
    split_x_kernel<<<(SEQ * DM) / (256 * 4), 256, 0, stream>>>(x, xhi, xlo, SEQ * DM);
    // 2. transpose+split weights
    dim3 wgrid(16, 16);
    wsplit_t_kernel<<<wgrid, 256, 0, stream>>>(Wq, Wqthi, Wqtlo);
    wsplit_t_kernel<<<wgrid, 256, 0, stream>>>(Wk, Wkthi, Wktlo);
    wsplit_t_kernel<<<wgrid, 256, 0, stream>>>(Wv, Wvthi, Wvtlo);
    // 3. projections (128-tile)
    dim3 pgrid(DM / 128, SEQ / 128);
    gemm128<0, DM><<<pgrid, 256, 0, stream>>>(xhi, xlo, Wqthi, Wqtlo, Qhi, Qlo, nullptr, nullptr, nullptr, nullptr);
    gemm128<0, DM><<<pgrid, 256, 0, stream>>>(xhi, xlo, Wkthi, Wktlo, Khi, Klo, nullptr, nullptr, nullptr, nullptr);
    gemm128<1, DM><<<pgrid, 256, 0, stream>>>(xhi, nullptr, Wvthi, nullptr, nullptr, nullptr, Vtmp, nullptr, nullptr, nullptr);
    // 4. transpose V
    transpose_f16<<<dim3(DM / 64, SEQ / 64), 256, 0, stream>>>(Vtmp, Vt);
    // 5. scores -> S16 (fp16 rel 64-col tile max) + T
    dim3 sgrid(SEQ / 128, SEQ / 128);
    gemm128<2, DM><<<sgrid, 256, 0, stream>>>(Qhi, Qlo, Khi, Klo, nullptr, nullptr, nullptr, nullptr, S16, T);
    // 6. row stats
    row_stats<<<SEQ, 256, 0, stream>>>(S16, T, Mr, Lr);
    // 7. S16 -> P (in place)
    p_pass<<<SEQ, 256, 0, stream>>>(S16, T, Mr, Lr);
    // 8. O = P @ V (plain f16 GEMM)
    gemm128<3, SEQ><<<dim3(DM / 128, SEQ / 128), 256, 0, stream>>>(
        (const unsigned short*)S16, nullptr, (const unsigned short*)Vt, nullptr,
        nullptr, nullptr, nullptr, Out, nullptr, nullptr);
}